// Round 10
// baseline (68.628 us; speedup 1.0000x reference)
//
#include <hip/hip_runtime.h>

// CTC loss forward (T=512, B=1024, C=63, S=25, L=51).
// One wave64 per batch element carrying BOTH directions (fwd alpha rows 1..255
// via wave-shr1, bwd beta rows 511..256 via wave-shl1), linear-domain
// recurrence with per-lane power-of-2 frames (no trans ops on the chain).
// Ring depth 24/dir, MANUALLY UNROLLED: r7-r9 showed the compiler abandons
// #pragma unroll once the fused epilogue grows the function (VGPR_Count=48 ->
// rings demoted to scratch, 2x slowdown). Literal slot indices make register
// residency unconditional.
// Fused deterministic reduction: per-sample nll -> 2^33 fixed-point u64
// atomicAdd (exactly commutative -> bitwise deterministic) + ticket;
// last wave publishes the batch mean.

#define TT 512
#define BB 1024
#define CC 63
#define SS 25
#define DP 24
#define NEGV (-1e30f)
#define LN2F 0.69314718055994531f
#define SCALE 8589934592.0   // 2^33

__device__ __forceinline__ float shr1f(float x, float fill) {  // lane s <- x[s-1]
  return __int_as_float(__builtin_amdgcn_update_dpp(
      __float_as_int(fill), __float_as_int(x), 0x138, 0xF, 0xF, false));
}
__device__ __forceinline__ int shr1i(int x, int fill) {
  return __builtin_amdgcn_update_dpp(fill, x, 0x138, 0xF, 0xF, false);
}
__device__ __forceinline__ float shl1f(float x, float fill) {  // lane s <- x[s+1]
  return __int_as_float(__builtin_amdgcn_update_dpp(
      __float_as_int(fill), __float_as_int(x), 0x130, 0xF, 0xF, false));
}
__device__ __forceinline__ int shl1i(int x, int fill) {
  return __builtin_amdgcn_update_dpp(fill, x, 0x130, 0xF, 0xF, false);
}
__device__ __forceinline__ int iclamp126(int d) {
  return d < -126 ? -126 : (d > 126 ? 126 : d);
}

__global__ __launch_bounds__(256, 1) void ctc_fb_kernel(
    const float* __restrict__ logp,
    const int* __restrict__ targets,
    const int* __restrict__ tlen,
    unsigned long long* __restrict__ wsum,
    unsigned int* __restrict__ wticket,
    float* __restrict__ out) {
  const int lane = threadIdx.x & 63;
  const int wid = threadIdx.x >> 6;
  const int b = (blockIdx.x << 2) + wid;           // 4 waves/block, 1 batch/wave
  const int* tg = targets + b * SS;
  const int len = tlen[b];

  // ext[s]: even s -> blank(0); odd s -> tg[(s-1)/2]
  int e = 0;
  float skf = 0.0f;   // fwd: inflow s-2 -> s allowed
  float skf2 = 0.0f;  // bwd: inflow s+2 -> s allowed
  if (lane & 1) {
    const int i = lane >> 1;
    if (i < SS) {
      e = tg[i];
      skf = (i == 0 || e != tg[i - 1]) ? 1.0f : 0.0f;
      if (i + 1 < SS) skf2 = (tg[i + 1] != tg[i]) ? 1.0f : 0.0f;
    }
  }

  const unsigned SB = (unsigned)(BB * CC) * 4u;    // bytes per timestep row block
  const char* base = (const char*)logp;
  const unsigned off0 = (unsigned)(b * CC + e) * 4u;
#define LDR(O) (*(const float*)(base + (O)))

  // fwd state
  float Af = (lane <= 1) ? __expf(LDR(off0)) : 0.0f;
  int M2f = 0;
  float F1f = 1.0f, F2f = skf;
  // bwd state (beta_511 init at final states)
  float Ab = (lane == 2 * len - 1 || lane == 2 * len) ? 1.0f : 0.0f;
  int M2b = 0;
  float F1b = 1.0f, F2b = skf2;

  // rings: pfF[j] = row 1+j ; pfB[j] = row 511-j  (filled with literal indices)
  float pfF[DP], pfB[DP];
  unsigned offF = off0 + SB;
  unsigned offB = off0 + 511u * SB;
#define FILL2(J) { pfF[J] = LDR(offF); offF += SB; pfB[J] = LDR(offB); offB -= SB; }
  FILL2(0) FILL2(1) FILL2(2) FILL2(3) FILL2(4) FILL2(5) FILL2(6) FILL2(7)
  FILL2(8) FILL2(9) FILL2(10) FILL2(11) FILL2(12) FILL2(13) FILL2(14) FILL2(15)
  FILL2(16) FILL2(17) FILL2(18) FILL2(19) FILL2(20) FILL2(21) FILL2(22) FILL2(23)
  // offF -> row 25 ; offB -> row 487

#define RENF() {                                               \
    int e2 = (int)(__float_as_uint(Af) >> 23) - 127;           \
    Af = ldexpf(Af, -e2);                                      \
    int m2n = M2f + e2;                                        \
    int m2a = shr1i(m2n, 0);                                   \
    M2f = (Af == 0.0f) ? m2a : m2n;                            \
    int s1 = shr1i(M2f, 0), s2 = shr1i(s1, 0);                 \
    F1f = ldexpf(1.0f, iclamp126(s1 - M2f));                   \
    F2f = skf * ldexpf(1.0f, iclamp126(s2 - M2f));             \
  }
#define RENB() {                                               \
    int e2 = (int)(__float_as_uint(Ab) >> 23) - 127;           \
    Ab = ldexpf(Ab, -e2);                                      \
    int m2n = M2b + e2;                                        \
    int m2a = shl1i(m2n, 0);                                   \
    M2b = (Ab == 0.0f) ? m2a : m2n;                            \
    int s1 = shl1i(M2b, 0), s2 = shl1i(s1, 0);                 \
    F1b = ldexpf(1.0f, iclamp126(s1 - M2b));                   \
    F2b = skf2 * ldexpf(1.0f, iclamp126(s2 - M2b));            \
  }
#define STEPF(J, PFLAG) {                                      \
    const float P = __expf(pfF[(J)]);                          \
    const float c1 = P * F1f, c2 = P * F2f;                    \
    const float x1 = shr1f(Af, 0.0f);                          \
    const float pa = P * Af;                                   \
    const float x2 = shr1f(x1, 0.0f);                          \
    Af = fmaf(c2, x2, fmaf(c1, x1, pa));                       \
    if (PFLAG) { pfF[(J)] = LDR(offF); offF += SB; }           \
  }
#define STEPB(J, PFLAG) {                                      \
    const float P = __expf(pfB[(J)]);                          \
    const float P1 = shl1f(P, 0.0f);                           \
    const float P2 = shl1f(P1, 0.0f);                          \
    const float c1 = F1b * P1, c2 = F2b * P2;                  \
    const float y1 = shl1f(Ab, 0.0f);                          \
    const float pb = P * Ab;                                   \
    const float y2 = shl1f(y1, 0.0f);                          \
    Ab = fmaf(c2, y2, fmaf(c1, y1, pb));                       \
    if (PFLAG) { pfB[(J)] = LDR(offB); offB -= SB; }           \
  }
#define PAIR_TT(JF, JB) { STEPF(JF, true) STEPB(JB, true) }
#define PAIR_FF(JF, JB) { STEPF(JF, false) STEPB(JB, false) }

  // peel k=0: bwd consumes row 511 (slot 0), refill with row 487
  STEPB(0, true)

  // main: k = 1 + 24*blk + j; fwd consumes row k (slot j),
  // bwd consumes row 511-k (slot (j+1)%24). Prefetch valid while k <= 231.
  for (int blk = 0; blk < 9; ++blk) {              // k = 1..216
    PAIR_TT(0, 1)  PAIR_TT(1, 2)  PAIR_TT(2, 3)  PAIR_TT(3, 4)
    PAIR_TT(4, 5)  PAIR_TT(5, 6)  PAIR_TT(6, 7)  PAIR_TT(7, 8)
    PAIR_TT(8, 9)  PAIR_TT(9, 10) PAIR_TT(10, 11) PAIR_TT(11, 12)
    RENF() RENB()
    PAIR_TT(12, 13) PAIR_TT(13, 14) PAIR_TT(14, 15) PAIR_TT(15, 16)
    PAIR_TT(16, 17) PAIR_TT(17, 18) PAIR_TT(18, 19) PAIR_TT(19, 20)
    PAIR_TT(20, 21) PAIR_TT(21, 22) PAIR_TT(22, 23) PAIR_TT(23, 0)
    RENF() RENB()
  }
  // blk 9: k = 217..240, prefetch iff j <= 14 (k <= 231)
  PAIR_TT(0, 1)  PAIR_TT(1, 2)  PAIR_TT(2, 3)  PAIR_TT(3, 4)
  PAIR_TT(4, 5)  PAIR_TT(5, 6)  PAIR_TT(6, 7)  PAIR_TT(7, 8)
  PAIR_TT(8, 9)  PAIR_TT(9, 10) PAIR_TT(10, 11) PAIR_TT(11, 12)
  RENF() RENB()
  PAIR_TT(12, 13) PAIR_TT(13, 14) PAIR_TT(14, 15)
  PAIR_FF(15, 16) PAIR_FF(16, 17) PAIR_FF(17, 18) PAIR_FF(18, 19)
  PAIR_FF(19, 20) PAIR_FF(20, 21) PAIR_FF(21, 22) PAIR_FF(22, 23)
  PAIR_FF(23, 0)
  RENF() RENB()
  // tail: k = 241..255 (15 steps), slots 0..14 hold rows 241..255
  PAIR_FF(0, 1)  PAIR_FF(1, 2)  PAIR_FF(2, 3)  PAIR_FF(3, 4)
  PAIR_FF(4, 5)  PAIR_FF(5, 6)  PAIR_FF(6, 7)  PAIR_FF(7, 8)
  PAIR_FF(8, 9)  PAIR_FF(9, 10) PAIR_FF(10, 11) PAIR_FF(11, 12)
  RENF() RENB()
  PAIR_FF(12, 13) PAIR_FF(13, 14) PAIR_FF(14, 15)

  // combine: ll = log sum_{s<=50} alpha_255[s] * beta_255[s]
  const float laf = fmaxf((float)M2f * LN2F + logf(Af), NEGV);
  const float lab = fmaxf((float)M2b * LN2F + logf(Ab), NEGV);
  float v = (lane <= 50) ? laf + lab : -2e30f;
  float m = v;
#pragma unroll
  for (int o = 32; o; o >>= 1) m = fmaxf(m, __shfl_xor(m, o));
  float s = __expf(v - m);
#pragma unroll
  for (int o = 32; o; o >>= 1) s += __shfl_xor(s, o);

  // fused deterministic reduction (lane 0 of each wave)
  if (lane == 0) {
    const float ll = m + logf(s);
    float nll = -ll;
    if (!(nll <= 0.5e30f)) nll = 0.0f;             // zero_infinity (also NaN)
    const int dl = len > 1 ? len : 1;
    const float smp = nll / (float)dl;             // per-sample loss (>= 0)
    const unsigned long long q = (unsigned long long)((double)smp * SCALE);
    atomicAdd(wsum, q);
    __threadfence();
    const unsigned t = atomicAdd(wticket, 1u);
    if (t == (unsigned)(BB - 1)) {                 // last wave: publish the mean
      __threadfence();
      const unsigned long long tot = atomicAdd(wsum, 0ull);  // coherent read
      out[0] = (float)(((double)tot / SCALE) / (double)BB);
    }
  }
}

extern "C" void kernel_launch(void* const* d_in, const int* in_sizes, int n_in,
                              void* d_out, int out_size, void* d_ws, size_t ws_size,
                              hipStream_t stream) {
  const float* logp  = (const float*)d_in[0];
  const int* targets = (const int*)d_in[1];
  const int* tlen    = (const int*)d_in[2];
  // ws[0..7]: u64 fixed-point sum; ws[8..11]: u32 ticket — zeroed each call
  hipMemsetAsync(d_ws, 0, 16, stream);
  hipLaunchKernelGGL(ctc_fb_kernel, dim3(BB / 4), dim3(256), 0, stream,
                     logp, targets, tlen,
                     (unsigned long long*)d_ws,
                     (unsigned int*)((char*)d_ws + 8),
                     (float*)d_out);
}

// Round 11
// 39.758 us; speedup vs baseline: 1.7262x; 1.7262x over previous
//
#include <hip/hip_runtime.h>

// CTC loss forward (T=512, B=1024, C=63, S=25, L=51).
// One wave64 per batch element carrying BOTH directions (fwd alpha rows 1..255
// via wave-shr1, bwd beta rows 511..256 via wave-shl1), linear-domain
// recurrence with per-lane power-of-2 frames (no trans ops on the chain).
// Ring depth 16/dir (easy register residency; prefetch distance ~3700 cy).
// Fused deterministic reduction WITHOUT __threadfence (r7-r10 lesson: each
// fence = L2 writeback; 1024 of them added ~30us idle tail):
//   per-block LDS u64 partial (fixed order) -> 1 atomicAdd + 1 ticket per
//   block (256 total); ordering via bare `s_waitcnt vmcnt(0)`; ticket winner
//   reads the total at the coherent point and publishes the mean.

#define TT 512
#define BB 1024
#define CC 63
#define SS 25
#define DP 16
#define NEGV (-1e30f)
#define LN2F 0.69314718055994531f
#define SCALE 8589934592.0   // 2^33

__device__ __forceinline__ float shr1f(float x, float fill) {  // lane s <- x[s-1]
  return __int_as_float(__builtin_amdgcn_update_dpp(
      __float_as_int(fill), __float_as_int(x), 0x138, 0xF, 0xF, false));
}
__device__ __forceinline__ int shr1i(int x, int fill) {
  return __builtin_amdgcn_update_dpp(fill, x, 0x138, 0xF, 0xF, false);
}
__device__ __forceinline__ float shl1f(float x, float fill) {  // lane s <- x[s+1]
  return __int_as_float(__builtin_amdgcn_update_dpp(
      __float_as_int(fill), __float_as_int(x), 0x130, 0xF, 0xF, false));
}
__device__ __forceinline__ int shl1i(int x, int fill) {
  return __builtin_amdgcn_update_dpp(fill, x, 0x130, 0xF, 0xF, false);
}
__device__ __forceinline__ int iclamp126(int d) {
  return d < -126 ? -126 : (d > 126 ? 126 : d);
}

__global__ __launch_bounds__(256) void ctc_fb_kernel(
    const float* __restrict__ logp,
    const int* __restrict__ targets,
    const int* __restrict__ tlen,
    unsigned long long* __restrict__ wsum,
    unsigned int* __restrict__ wticket,
    float* __restrict__ out) {
  const int lane = threadIdx.x & 63;
  const int wid = threadIdx.x >> 6;
  const int b = (blockIdx.x << 2) + wid;           // 4 waves/block, 1 batch/wave
  const int* tg = targets + b * SS;
  const int len = tlen[b];

  // ext[s]: even s -> blank(0); odd s -> tg[(s-1)/2]
  int e = 0;
  float skf = 0.0f;   // fwd: inflow s-2 -> s allowed
  float skf2 = 0.0f;  // bwd: inflow s+2 -> s allowed
  if (lane & 1) {
    const int i = lane >> 1;
    if (i < SS) {
      e = tg[i];
      skf = (i == 0 || e != tg[i - 1]) ? 1.0f : 0.0f;
      if (i + 1 < SS) skf2 = (tg[i + 1] != tg[i]) ? 1.0f : 0.0f;
    }
  }

  const unsigned SB = (unsigned)(BB * CC) * 4u;    // bytes per timestep row block
  const char* base = (const char*)logp;
  const unsigned off0 = (unsigned)(b * CC + e) * 4u;
#define LDR(O) (*(const float*)(base + (O)))

  // fwd state
  float Af = (lane <= 1) ? __expf(LDR(off0)) : 0.0f;
  int M2f = 0;
  float F1f = 1.0f, F2f = skf;
  // bwd state (beta_511 init at final states)
  float Ab = (lane == 2 * len - 1 || lane == 2 * len) ? 1.0f : 0.0f;
  int M2b = 0;
  float F1b = 1.0f, F2b = skf2;

  // rings: pfF[j] = row 1+j ; pfB[j] = row 511-j
  float pfF[DP], pfB[DP];
  unsigned offF = off0 + SB;
  unsigned offB = off0 + 511u * SB;
#pragma unroll
  for (int j = 0; j < DP; ++j) {
    pfF[j] = LDR(offF); offF += SB;
    pfB[j] = LDR(offB); offB -= SB;
  }
  // offF -> row 17 ; offB -> row 495

#define RENF() {                                               \
    int e2 = (int)(__float_as_uint(Af) >> 23) - 127;           \
    Af = ldexpf(Af, -e2);                                      \
    int m2n = M2f + e2;                                        \
    int m2a = shr1i(m2n, 0);                                   \
    M2f = (Af == 0.0f) ? m2a : m2n;                            \
    int s1 = shr1i(M2f, 0), s2 = shr1i(s1, 0);                 \
    F1f = ldexpf(1.0f, iclamp126(s1 - M2f));                   \
    F2f = skf * ldexpf(1.0f, iclamp126(s2 - M2f));             \
  }
#define RENB() {                                               \
    int e2 = (int)(__float_as_uint(Ab) >> 23) - 127;           \
    Ab = ldexpf(Ab, -e2);                                      \
    int m2n = M2b + e2;                                        \
    int m2a = shl1i(m2n, 0);                                   \
    M2b = (Ab == 0.0f) ? m2a : m2n;                            \
    int s1 = shl1i(M2b, 0), s2 = shl1i(s1, 0);                 \
    F1b = ldexpf(1.0f, iclamp126(s1 - M2b));                   \
    F2b = skf2 * ldexpf(1.0f, iclamp126(s2 - M2b));            \
  }
#define STEPF(J, PFLAG) {                                      \
    const float P = __expf(pfF[(J)]);                          \
    const float c1 = P * F1f, c2 = P * F2f;                    \
    const float x1 = shr1f(Af, 0.0f);                          \
    const float pa = P * Af;                                   \
    const float x2 = shr1f(x1, 0.0f);                          \
    Af = fmaf(c2, x2, fmaf(c1, x1, pa));                       \
    if (PFLAG) { pfF[(J)] = LDR(offF); offF += SB; }           \
  }
#define STEPB(J, PFLAG) {                                      \
    const float P = __expf(pfB[(J)]);                          \
    const float P1 = shl1f(P, 0.0f);                           \
    const float P2 = shl1f(P1, 0.0f);                          \
    const float c1 = F1b * P1, c2 = F2b * P2;                  \
    const float y1 = shl1f(Ab, 0.0f);                          \
    const float pb = P * Ab;                                   \
    const float y2 = shl1f(y1, 0.0f);                          \
    Ab = fmaf(c2, y2, fmaf(c1, y1, pb));                       \
    if (PFLAG) { pfB[(J)] = LDR(offB); offB -= SB; }           \
  }

  // peel k=0: bwd consumes row 511 (slot 0), refill with row 495
  STEPB(0, true)

  // main pairs k = 1..255: fwd row k (slot (k-1)&15), bwd row 511-k (slot k&15).
  // Refill at pair k loads fwd row k+16 / bwd row 495-k; valid iff k <= 239.
  for (int blk = 0; blk < 14; ++blk) {             // k = 1..224
#pragma unroll
    for (int j = 0; j < DP; ++j) {
      STEPF(j, true)
      STEPB((j + 1) & 15, true)
      if (j == 15) { RENF() RENB() }
    }
  }
  // blk 14: k = 225..240, prefetch iff j <= 14 (k <= 239)
#pragma unroll
  for (int j = 0; j < DP; ++j) {
    STEPF(j, j <= 14)
    STEPB((j + 1) & 15, j <= 14)
    if (j == 15) { RENF() RENB() }
  }
  // tail: k = 241..255 (15 pairs), no prefetch
#pragma unroll
  for (int j = 0; j < 15; ++j) {
    STEPF(j, false)
    STEPB(j + 1, false)
  }

  // combine: ll = log sum_{s<=50} alpha_255[s] * beta_255[s]
  const float laf = fmaxf((float)M2f * LN2F + logf(Af), NEGV);
  const float lab = fmaxf((float)M2b * LN2F + logf(Ab), NEGV);
  float v = (lane <= 50) ? laf + lab : -2e30f;
  float m = v;
#pragma unroll
  for (int o = 32; o; o >>= 1) m = fmaxf(m, __shfl_xor(m, o));
  float s = __expf(v - m);
#pragma unroll
  for (int o = 32; o; o >>= 1) s += __shfl_xor(s, o);

  // per-block deterministic partial (fixed-point u64), then ONE atomic/block
  __shared__ unsigned long long part[4];
  if (lane == 0) {
    const float ll = m + logf(s);
    float nll = -ll;
    if (!(nll <= 0.5e30f)) nll = 0.0f;             // zero_infinity (also NaN)
    const int dl = len > 1 ? len : 1;
    const float smp = nll / (float)dl;             // per-sample loss (>= 0)
    part[wid] = (unsigned long long)((double)smp * SCALE);
  }
  __syncthreads();
  if (threadIdx.x == 0) {
    const unsigned long long sum4 = part[0] + part[1] + part[2] + part[3];
    const unsigned long long old = atomicAdd(wsum, sum4);
    // my add must be globally performed before my ticket: bare completion
    // wait on the returning atomic (NO buffer_wbl2 / cache writeback).
    asm volatile("s_waitcnt vmcnt(0)" :: "v"(old) : "memory");
    const unsigned t = atomicAdd(wticket, 1u);
    if (t == (unsigned)gridDim.x - 1u) {           // last block: publish mean
      const unsigned long long tot = atomicAdd(wsum, 0ull);  // coherent read
      out[0] = (float)(((double)tot / SCALE) / (double)BB);
    }
  }
}

extern "C" void kernel_launch(void* const* d_in, const int* in_sizes, int n_in,
                              void* d_out, int out_size, void* d_ws, size_t ws_size,
                              hipStream_t stream) {
  const float* logp  = (const float*)d_in[0];
  const int* targets = (const int*)d_in[1];
  const int* tlen    = (const int*)d_in[2];
  // ws[0..7]: u64 fixed-point sum; ws[8..11]: u32 ticket — zeroed each call
  hipMemsetAsync(d_ws, 0, 16, stream);
  hipLaunchKernelGGL(ctc_fb_kernel, dim3(BB / 4), dim3(256), 0, stream,
                     logp, targets, tlen,
                     (unsigned long long*)d_ws,
                     (unsigned int*)((char*)d_ws + 8),
                     (float*)d_out);
}

// Round 12
// 32.017 us; speedup vs baseline: 2.1435x; 1.2418x over previous
//
#include <hip/hip_runtime.h>

// CTC loss forward (T=512, B=1024, C=63, S=25, L=51).
// One wave64 per batch element carrying BOTH directions (fwd alpha rows 1..255
// via wave-shr1, bwd beta rows 511..256 via wave-shl1), linear-domain
// recurrence with per-lane power-of-2 frames. 2 loads/step/wave saturates the
// per-CU VMEM line-delivery wall (~9.5 B/cy/CU, 93% of m13 ceiling; confirmed
// across 4 structural variants r3-r6). Combine intra-wave; per-sample loss to
// d_ws; separate 1-block deterministic reduce (r7-r11: every fused-epilogue
// variant regressed 8-37us via scratch demotion / fence writebacks).
// This is r6 verbatim — the proven 31.9us configuration.

#define TT 512
#define BB 1024
#define CC 63
#define SS 25
#define DP 24
#define NEGV (-1e30f)
#define LN2F 0.69314718055994531f

__device__ __forceinline__ float shr1f(float x, float fill) {  // lane s <- x[s-1]
  return __int_as_float(__builtin_amdgcn_update_dpp(
      __float_as_int(fill), __float_as_int(x), 0x138, 0xF, 0xF, false));
}
__device__ __forceinline__ int shr1i(int x, int fill) {
  return __builtin_amdgcn_update_dpp(fill, x, 0x138, 0xF, 0xF, false);
}
__device__ __forceinline__ float shl1f(float x, float fill) {  // lane s <- x[s+1]
  return __int_as_float(__builtin_amdgcn_update_dpp(
      __float_as_int(fill), __float_as_int(x), 0x130, 0xF, 0xF, false));
}
__device__ __forceinline__ int shl1i(int x, int fill) {
  return __builtin_amdgcn_update_dpp(fill, x, 0x130, 0xF, 0xF, false);
}
__device__ __forceinline__ int iclamp126(int d) {
  return d < -126 ? -126 : (d > 126 ? 126 : d);
}

__global__ __launch_bounds__(256) void ctc_fb_kernel(
    const float* __restrict__ logp,
    const int* __restrict__ targets,
    const int* __restrict__ tlen,
    float* __restrict__ loss) {
  const int lane = threadIdx.x & 63;
  const int wid = threadIdx.x >> 6;
  const int b = (blockIdx.x << 2) + wid;           // 4 waves/block, 1 batch/wave
  const int* tg = targets + b * SS;
  const int len = tlen[b];

  // ext[s]: even s -> blank(0); odd s -> tg[(s-1)/2]
  int e = 0;
  float skf = 0.0f;   // fwd: inflow s-2 -> s allowed
  float skf2 = 0.0f;  // bwd: inflow s+2 -> s allowed
  if (lane & 1) {
    const int i = lane >> 1;
    if (i < SS) {
      e = tg[i];
      skf = (i == 0 || e != tg[i - 1]) ? 1.0f : 0.0f;
      if (i + 1 < SS) skf2 = (tg[i + 1] != tg[i]) ? 1.0f : 0.0f;
    }
  }

  const unsigned SB = (unsigned)(BB * CC) * 4u;    // bytes per timestep row block
  const char* base = (const char*)logp;
  const unsigned off0 = (unsigned)(b * CC + e) * 4u;
#define LDR(O) (*(const float*)(base + (O)))

  // fwd state
  float Af = (lane <= 1) ? __expf(LDR(off0)) : 0.0f;
  int M2f = 0;
  float F1f = 1.0f, F2f = skf;
  // bwd state (beta_511 init at final states)
  float Ab = (lane == 2 * len - 1 || lane == 2 * len) ? 1.0f : 0.0f;
  int M2b = 0;
  float F1b = 1.0f, F2b = skf2;

  // rings: pfF[j] = row 1+j ; pfB[j] = row 511-j
  float pfF[DP], pfB[DP];
  unsigned offF = off0 + SB;
  unsigned offB = off0 + 511u * SB;
#pragma unroll
  for (int j = 0; j < DP; ++j) {
    pfF[j] = LDR(offF); offF += SB;
    pfB[j] = LDR(offB); offB -= SB;
  }
  // offF -> row 25 ; offB -> row 487

#define RENF() {                                               \
    int e2 = (int)(__float_as_uint(Af) >> 23) - 127;           \
    Af = ldexpf(Af, -e2);                                      \
    int m2n = M2f + e2;                                        \
    int m2a = shr1i(m2n, 0);                                   \
    M2f = (Af == 0.0f) ? m2a : m2n;                            \
    int s1 = shr1i(M2f, 0), s2 = shr1i(s1, 0);                 \
    F1f = ldexpf(1.0f, iclamp126(s1 - M2f));                   \
    F2f = skf * ldexpf(1.0f, iclamp126(s2 - M2f));             \
  }
#define RENB() {                                               \
    int e2 = (int)(__float_as_uint(Ab) >> 23) - 127;           \
    Ab = ldexpf(Ab, -e2);                                      \
    int m2n = M2b + e2;                                        \
    int m2a = shl1i(m2n, 0);                                   \
    M2b = (Ab == 0.0f) ? m2a : m2n;                            \
    int s1 = shl1i(M2b, 0), s2 = shl1i(s1, 0);                 \
    F1b = ldexpf(1.0f, iclamp126(s1 - M2b));                   \
    F2b = skf2 * ldexpf(1.0f, iclamp126(s2 - M2b));            \
  }
#define STEPF(J, PFLAG) {                                      \
    const float P = __expf(pfF[(J)]);                          \
    const float c1 = P * F1f, c2 = P * F2f;                    \
    const float x1 = shr1f(Af, 0.0f);                          \
    const float pa = P * Af;                                   \
    const float x2 = shr1f(x1, 0.0f);                          \
    Af = fmaf(c2, x2, fmaf(c1, x1, pa));                       \
    if (PFLAG) { pfF[(J)] = LDR(offF); offF += SB; }           \
  }
#define STEPB(J, PFLAG) {                                      \
    const float P = __expf(pfB[(J)]);                          \
    const float P1 = shl1f(P, 0.0f);                           \
    const float P2 = shl1f(P1, 0.0f);                          \
    const float c1 = F1b * P1, c2 = F2b * P2;                  \
    const float y1 = shl1f(Ab, 0.0f);                          \
    const float pb = P * Ab;                                   \
    const float y2 = shl1f(y1, 0.0f);                          \
    Ab = fmaf(c2, y2, fmaf(c1, y1, pb));                       \
    if (PFLAG) { pfB[(J)] = LDR(offB); offB -= SB; }           \
  }

  // peel k=0: bwd consumes row 511 (slot 0), refill with row 487
  STEPB(0, true)

  // main: k = 1 + 24*blk + j; fwd consumes row k (slot j),
  // bwd consumes row 511-k (slot (j+1)%24). Prefetch valid while k <= 231.
  for (int blk = 0; blk < 9; ++blk) {              // k = 1..216
#pragma unroll
    for (int j = 0; j < DP; ++j) {
      STEPF(j, true)
      STEPB((j + 1) % DP, true)
      if (j == 11 || j == 23) { RENF() RENB() }
    }
  }
  // blk 9: k = 217..240, prefetch iff j <= 14 (k <= 231)
#pragma unroll
  for (int j = 0; j < DP; ++j) {
    STEPF(j, j <= 14)
    STEPB((j + 1) % DP, j <= 14)
    if (j == 11 || j == 23) { RENF() RENB() }
  }
  // tail: k = 241..255 (15 steps), no prefetch
#pragma unroll
  for (int j = 0; j < 15; ++j) {
    STEPF(j, false)
    STEPB(j + 1, false)
    if (j == 11) { RENF() RENB() }
  }

  // combine: ll = log sum_{s<=50} alpha_255[s] * beta_255[s]
  const float laf = fmaxf((float)M2f * LN2F + logf(Af), NEGV);
  const float lab = fmaxf((float)M2b * LN2F + logf(Ab), NEGV);
  float v = (lane <= 50) ? laf + lab : -2e30f;
  float m = v;
#pragma unroll
  for (int o = 32; o; o >>= 1) m = fmaxf(m, __shfl_xor(m, o));
  float s = __expf(v - m);
#pragma unroll
  for (int o = 32; o; o >>= 1) s += __shfl_xor(s, o);
  if (lane == 0) {
    const float ll = m + logf(s);
    float nll = -ll;
    if (!(nll <= 0.5e30f)) nll = 0.0f;   // zero_infinity (also NaN)
    const int dl = len > 1 ? len : 1;
    loss[b] = nll / (float)dl;
  }
}

__global__ __launch_bounds__(256) void ctc_reduce_kernel(
    const float* __restrict__ loss, float* __restrict__ out) {
  float s = 0.f;
  for (int i = threadIdx.x; i < BB; i += 256) s += loss[i];
#pragma unroll
  for (int off = 32; off; off >>= 1) s += __shfl_down(s, off);
  __shared__ float sm[4];
  if ((threadIdx.x & 63) == 0) sm[threadIdx.x >> 6] = s;
  __syncthreads();
  if (threadIdx.x == 0) out[0] = (sm[0] + sm[1] + sm[2] + sm[3]) / (float)BB;
}

extern "C" void kernel_launch(void* const* d_in, const int* in_sizes, int n_in,
                              void* d_out, int out_size, void* d_ws, size_t ws_size,
                              hipStream_t stream) {
  const float* logp  = (const float*)d_in[0];
  const int* targets = (const int*)d_in[1];
  const int* tlen    = (const int*)d_in[2];
  float* out  = (float*)d_out;
  float* loss = (float*)d_ws;   // B floats of per-sample loss
  hipLaunchKernelGGL(ctc_fb_kernel, dim3(BB / 4), dim3(256), 0, stream,
                     logp, targets, tlen, loss);
  hipLaunchKernelGGL(ctc_reduce_kernel, dim3(1), dim3(256), 0, stream, loss, out);
}